// Round 12
// baseline (319.602 us; speedup 1.0000x reference)
//
#include <hip/hip_runtime.h>

typedef __attribute__((ext_vector_type(4))) float f32x4;
typedef __attribute__((ext_vector_type(8))) short bf16x8;
typedef unsigned long long u64;
typedef unsigned short u16;
typedef unsigned int u32;

// round-to-nearest-even f32 -> bf16 bits
static __device__ __forceinline__ u16 f2bf(float f) {
    u32 u = __float_as_uint(f);
    u += 0x7fffu + ((u >> 16) & 1u);
    return (u16)(u >> 16);
}

// ---------------- kernel 1: s[g][ic] = style[g] . mod_w[ic] + mod_b[ic] ----
__global__ void k_style(const float* __restrict__ style, const float* __restrict__ mod_w,
                        const float* __restrict__ mod_b, float* __restrict__ s_ws) {
    int t = blockIdx.x * 256 + threadIdx.x;     // 0..2047
    int g = t >> 9, ic = t & 511;
    const f32x4* st = (const f32x4*)(style + (g << 9));
    const f32x4* mw = (const f32x4*)(mod_w + (ic << 9));
    float acc = 0.f;
#pragma unroll 4
    for (int d = 0; d < 128; ++d) {
        f32x4 a = st[d], b = mw[d];
        acc += a[0]*b[0] + a[1]*b[1] + a[2]*b[2] + a[3]*b[3];
    }
    s_ws[t] = acc + mod_b[ic];
}

// ---------------- kernel 2: Wmod bf16, fragment-lane order ----------------
// Layout: [g(4)][ocb(4)][wr(2)][ch(16)][tap(9)][m(4)][lane(64)][e(8)]
// oc = ocb*128 + wr*64 + m*16 + (lane&15) ; ic = ch*32 + (lane>>4)*8 + e
__global__ void k_wmod(const float* __restrict__ weight, const float* __restrict__ demod,
                       const float* __restrict__ s_ws, short* __restrict__ wmod) {
    int t = blockIdx.x * 256 + threadIdx.x;     // [0, 131072)
    int lane = t & 63; int r = t >> 6;
    int m = r & 3; r >>= 2;
    int ch = r & 15; r >>= 4;
    int wr = r & 1; r >>= 1;
    int ocb = r & 3; r >>= 2;
    int g = r & 3;
    int oc  = ocb*128 + wr*64 + m*16 + (lane & 15);
    int ic0 = ch*32 + (lane >> 4)*8;
    const float* wp = weight + (size_t)(oc*512 + ic0)*9;   // 72 contiguous floats
    float sv[8];
#pragma unroll
    for (int e = 0; e < 8; ++e) sv[e] = s_ws[(g << 9) + ic0 + e] * demod[ic0 + e];
    short* base = wmod + ((size_t)((g*4 + ocb)*2 + wr)) * 294912 + ((size_t)m << 9) + (lane << 3);
#pragma unroll
    for (int tp = 0; tp < 9; ++tp) {
        bf16x8 pk;
#pragma unroll
        for (int e = 0; e < 8; ++e) pk[e] = (short)f2bf(wp[e*9 + tp] * sv[e]);
        *(bf16x8*)&base[(size_t)(ch*9 + tp) << 11] = pk;
    }
}

// ---------------- kernel 2b: x fp32 NCHW -> bf16 swizzled [ch][px][k][e] ---
// xb row (nb,g,y): [ch(16)][px(64)][k(4)][e(8)]; physical k holds logical
// k' = k ^ ((px>>1)&3)  (bank swizzle baked into global layout)
__global__ __launch_bounds__(256) void k_xcast(const float* __restrict__ x,
                                               short* __restrict__ xb) {
    __shared__ short Ls[64 * 520];      // row stride 520 shorts (16B-aligned)
    const int tid = threadIdx.x;
    const int y = blockIdx.x, g = blockIdx.y, nb = blockIdx.z;
    const float* src = x + (((size_t)(nb * 2048 + (g << 9))) << 12) + (y << 6);
#pragma unroll
    for (int it = 0; it < 32; ++it) {
        int j = it * 256 + tid;         // (ic, px-quad)
        int ic = j >> 4, p4 = j & 15;
        f32x4 v = *(const f32x4*)(src + ((size_t)ic << 12) + (p4 << 2));
        int kk = (ic >> 3) & 3;
        int fb = (ic >> 5) * 32 + (ic & 7);    // ch*32 + e
#pragma unroll
        for (int c = 0; c < 4; ++c) {
            int px = (p4 << 2) + c;
            int k = kk ^ ((px >> 1) & 3);
            Ls[px * 520 + fb + k * 8] = (short)f2bf(v[c]);
        }
    }
    __syncthreads();
    short* dstb = xb + ((size_t)((nb * 4 + g) * 64 + y) << 15);
#pragma unroll
    for (int it = 0; it < 16; ++it) {
        int j = it * 256 + tid;         // (ch,px,k)
        int ch = j >> 8, px = (j >> 2) & 63, k = j & 3;
        *(bf16x8*)&dstb[(size_t)j << 3] = *(const bf16x8*)&Ls[px * 520 + ch * 32 + k * 8];
    }
}

// ---------------- kernel 3: main implicit-GEMM conv (16x16x32 MFMA) --------
// Block 128oc x 128px (2 rows), 4 waves (wr2 x wc2), each 64oc x 64px
// (acc 4x4 = 64 AGPR). BK=32, 16 chunks, 9 taps/chunk = 144 steps.
// CHUNK-PHASE STAGGER: co-resident blocks (linear ids spaced 256 under
// round-robin dispatch) start their chunk loop at phases 0/4/8/12 ->
// barrier/serial-head stalls decorrelate across blocks on one CU, so other
// blocks' MFMAs fill the matrix pipe (R11: occupancy raise alone was null ->
// stalls are synchronized; this breaks the synchronization).
// K-chunk order is accumulation-order-free (independent f32 partial sums).
// W: global->register depth-1 pipeline, per-chunk base (wcur/wnxt).
// X: global_load_lds into double-buffered LDS (buffer parity by loop iter).
// Barrier = s_waitcnt vmcnt(4) + s_barrier (T4); setprio on MFMA (T5).
__global__ __launch_bounds__(256, 4) void k_conv(const short* __restrict__ xb,
                                                 const short* __restrict__ wmod,
                                                 float* __restrict__ out) {
    __shared__ __align__(16) short Xs[2 * 8448];   // 33792 B

    const int tid  = threadIdx.x;
    const int lane = tid & 63;
    const int wv   = tid >> 6;
    const int wr   = wv >> 1, wc = wv & 1;
    const int l15  = lane & 15;
    const int l4   = lane >> 4;
    const int ocb  = blockIdx.x >> 5, rowb = blockIdx.x & 31;
    const int g    = blockIdx.y, nb = blockIdx.z;
    const int y0   = rowb << 1;

    // chunk-phase: co-residents (linear spaced 256) -> phases 0,4,8,12
    const int linear  = blockIdx.x + (blockIdx.y << 7) + (blockIdx.z << 9);
    const int chStart = ((linear >> 8) << 2) & 15;

    const short* xbg = xb + ((size_t)((nb * 4 + g) * 64) << 15);
    const short* wg  = wmod + ((size_t)((g * 4 + ocb) * 2 + wr)) * 294912;
    float* outg = out + (((size_t)(nb * 2048 + (g << 9) + ocb * 128)) << 12) + (rowb << 7);

    // staging: this wave stages image row gy = y0-1+wv
    const int gy = y0 - 1 + wv;
    const bool srow = (gy >= 0 && gy <= 63);
    const short* xsrc = xbg + ((size_t)(srow ? gy : 0) << 15) + (lane << 3);
    short* xdst0 = Xs + ((wv * 66 + 1) << 5);

    const short* wl = wg + (lane << 3);   // per-lane W base

    // zero both buffers (pad slots + out-of-range halo rows stay 0 forever)
    for (int i = tid; i < 4224; i += 256) ((u64*)Xs)[i] = 0ull;

    f32x4 acc[4][4];
#pragma unroll
    for (int m = 0; m < 4; ++m)
#pragma unroll
        for (int nn = 0; nn < 4; ++nn) acc[m][nn] = (f32x4){0.f, 0.f, 0.f, 0.f};

    __syncthreads();                    // zeros visible before any gload_lds lands

    // prologue: stage chunk chStart -> buf 0 (oldest in vmcnt), W tap-0 prefetch
    if (srow) {
        const short* s0 = xsrc + ((size_t)chStart << 11);
#pragma unroll
        for (int q = 0; q < 4; ++q)
            __builtin_amdgcn_global_load_lds(
                (const __attribute__((address_space(1))) void*)(s0 + (q << 9)),
                (__attribute__((address_space(3))) void*)(xdst0 + (q << 9)), 16, 0, 0);
    }
    __builtin_amdgcn_sched_barrier(0);
    {
        const short* w0 = wl + chStart * 18432;
        __builtin_amdgcn_sched_barrier(0);
        // loads below
        // (na declared after to keep live range tight)
    }
    const short* w0 = wl + chStart * 18432;
    bf16x8 na0 = *(const bf16x8*)(w0);
    bf16x8 na1 = *(const bf16x8*)(w0 + 512);
    bf16x8 na2 = *(const bf16x8*)(w0 + 1024);
    bf16x8 na3 = *(const bf16x8*)(w0 + 1536);

#pragma unroll 1
    for (int ch = 0; ch < 16; ++ch) {
        // T4 barrier: all but the 4 newest (next tap's W) have landed
        asm volatile("s_waitcnt vmcnt(4)" ::: "memory");
        __builtin_amdgcn_s_barrier();
        __builtin_amdgcn_sched_barrier(0);
        if (ch < 15 && srow) {          // stage next rotated chunk into other buffer
            const int chN = (chStart + ch + 1) & 15;
            const short* s = xsrc + ((size_t)chN << 11);
            short* d = xdst0 + (((ch + 1) & 1) ? 8448 : 0);
#pragma unroll
            for (int q = 0; q < 4; ++q)
                __builtin_amdgcn_global_load_lds(
                    (const __attribute__((address_space(1))) void*)(s + (q << 9)),
                    (__attribute__((address_space(3))) void*)(d + (q << 9)), 16, 0, 0);
        }
        __builtin_amdgcn_sched_barrier(0);   // pin stage issue before tap work
        const int bb = (ch & 1) * 8448;

        // W bases for this (rotated) chunk and the next
        const int curW = (chStart + ch) & 15;
        const int nxtW = (curW + 1) & 15;
        const short* wcur = wl + curW * 18432;
        const short* wnxt = wl + nxtW * 18432;

        // per-dx B base offsets at dy=-1 (buffer row = wc); per tap add
        // (dy+1)*2112 shorts. Swizzle: physical k = l4 ^ (((l15+dx)>>1)&3).
        int pB[3];
#pragma unroll
        for (int d = 0; d < 3; ++d) {
            const int dx = d - 1;
            pB[d] = bb + ((wc * 66 + 1 + dx + l15) << 5)
                  + ((l4 ^ (((l15 + dx) >> 1) & 3)) << 3);
        }

#pragma unroll
        for (int tap = 0; tap < 9; ++tap) {
            // depth-1 W pipeline: consume na, prefetch next tap (or next
            // chunk's tap 0 when tap==8; tap is compile-time under unroll)
            bf16x8 ca0 = na0, ca1 = na1, ca2 = na2, ca3 = na3;
            const short* wp2 = (tap < 8) ? (wcur + (tap + 1) * 2048) : wnxt;
            na0 = *(const bf16x8*)(wp2);
            na1 = *(const bf16x8*)(wp2 + 512);
            na2 = *(const bf16x8*)(wp2 + 1024);
            na3 = *(const bf16x8*)(wp2 + 1536);

            const int p0 = pB[tap % 3] + (tap / 3) * 2112;
            bf16x8 b0 = *(const bf16x8*)&Xs[p0];
            bf16x8 b1 = *(const bf16x8*)&Xs[p0 + 512];
            bf16x8 b2 = *(const bf16x8*)&Xs[p0 + 1024];
            bf16x8 b3 = *(const bf16x8*)&Xs[p0 + 1536];

            __builtin_amdgcn_s_setprio(1);
            acc[0][0] = __builtin_amdgcn_mfma_f32_16x16x32_bf16(ca0, b0, acc[0][0], 0, 0, 0);
            acc[1][0] = __builtin_amdgcn_mfma_f32_16x16x32_bf16(ca1, b0, acc[1][0], 0, 0, 0);
            acc[2][0] = __builtin_amdgcn_mfma_f32_16x16x32_bf16(ca2, b0, acc[2][0], 0, 0, 0);
            acc[3][0] = __builtin_amdgcn_mfma_f32_16x16x32_bf16(ca3, b0, acc[3][0], 0, 0, 0);
            acc[0][1] = __builtin_amdgcn_mfma_f32_16x16x32_bf16(ca0, b1, acc[0][1], 0, 0, 0);
            acc[1][1] = __builtin_amdgcn_mfma_f32_16x16x32_bf16(ca1, b1, acc[1][1], 0, 0, 0);
            acc[2][1] = __builtin_amdgcn_mfma_f32_16x16x32_bf16(ca2, b1, acc[2][1], 0, 0, 0);
            acc[3][1] = __builtin_amdgcn_mfma_f32_16x16x32_bf16(ca3, b1, acc[3][1], 0, 0, 0);
            acc[0][2] = __builtin_amdgcn_mfma_f32_16x16x32_bf16(ca0, b2, acc[0][2], 0, 0, 0);
            acc[1][2] = __builtin_amdgcn_mfma_f32_16x16x32_bf16(ca1, b2, acc[1][2], 0, 0, 0);
            acc[2][2] = __builtin_amdgcn_mfma_f32_16x16x32_bf16(ca2, b2, acc[2][2], 0, 0, 0);
            acc[3][2] = __builtin_amdgcn_mfma_f32_16x16x32_bf16(ca3, b2, acc[3][2], 0, 0, 0);
            acc[0][3] = __builtin_amdgcn_mfma_f32_16x16x32_bf16(ca0, b3, acc[0][3], 0, 0, 0);
            acc[1][3] = __builtin_amdgcn_mfma_f32_16x16x32_bf16(ca1, b3, acc[1][3], 0, 0, 0);
            acc[2][3] = __builtin_amdgcn_mfma_f32_16x16x32_bf16(ca2, b3, acc[2][3], 0, 0, 0);
            acc[3][3] = __builtin_amdgcn_mfma_f32_16x16x32_bf16(ca3, b3, acc[3][3], 0, 0, 0);
            __builtin_amdgcn_s_setprio(0);
        }
    }

    // ---- epilogue: C/D layout col=lane&15 (pixel), row=(lane>>4)*4+r (oc) ----
#pragma unroll
    for (int m = 0; m < 4; ++m)
#pragma unroll
        for (int nn = 0; nn < 4; ++nn) {
            const int oc = (wr << 6) + (m << 4) + (l4 << 2);
            const int p  = (wc << 6) + (nn << 4) + l15;
            float* dst = outg + ((size_t)oc << 12) + p;
#pragma unroll
            for (int r = 0; r < 4; ++r) dst[(size_t)r << 12] = acc[m][nn][r];
        }
}

extern "C" void kernel_launch(void* const* d_in, const int* in_sizes, int n_in,
                              void* d_out, int out_size, void* d_ws, size_t ws_size,
                              hipStream_t stream) {
    const float* x      = (const float*)d_in[0];
    const float* style  = (const float*)d_in[1];
    const float* weight = (const float*)d_in[2];
    const float* demod  = (const float*)d_in[3];
    const float* mod_w  = (const float*)d_in[4];
    const float* mod_b  = (const float*)d_in[5];
    float* out = (float*)d_out;

    float* s_ws = (float*)d_ws;                           // 8 KB
    short* wmod = (short*)((char*)d_ws + 8192);           // 18.9 MB
    short* xbuf = (short*)((char*)d_ws + 8192 + 18874368);// 67.1 MB (total ~86 MB)

    hipLaunchKernelGGL(k_style, dim3(8), dim3(256), 0, stream, style, mod_w, mod_b, s_ws);
    hipLaunchKernelGGL(k_wmod, dim3(512), dim3(256), 0, stream, weight, demod, s_ws, wmod);
    hipLaunchKernelGGL(k_xcast, dim3(64, 4, 4), dim3(256), 0, stream, x, xbuf);
    hipLaunchKernelGGL(k_conv, dim3(128, 4, 4), dim3(256), 0, stream, xbuf, wmod, out);
}

// Round 13
// 315.336 us; speedup vs baseline: 1.0135x; 1.0135x over previous
//
#include <hip/hip_runtime.h>

typedef __attribute__((ext_vector_type(4))) float f32x4;
typedef __attribute__((ext_vector_type(8))) short bf16x8;
typedef unsigned long long u64;
typedef unsigned short u16;
typedef unsigned int u32;

// round-to-nearest-even f32 -> bf16 bits
static __device__ __forceinline__ u16 f2bf(float f) {
    u32 u = __float_as_uint(f);
    u += 0x7fffu + ((u >> 16) & 1u);
    return (u16)(u >> 16);
}

// ---------------- kernel 1: s[g][ic] = style[g] . mod_w[ic] + mod_b[ic] ----
__global__ void k_style(const float* __restrict__ style, const float* __restrict__ mod_w,
                        const float* __restrict__ mod_b, float* __restrict__ s_ws) {
    int t = blockIdx.x * 256 + threadIdx.x;     // 0..2047
    int g = t >> 9, ic = t & 511;
    const f32x4* st = (const f32x4*)(style + (g << 9));
    const f32x4* mw = (const f32x4*)(mod_w + (ic << 9));
    float acc = 0.f;
#pragma unroll 4
    for (int d = 0; d < 128; ++d) {
        f32x4 a = st[d], b = mw[d];
        acc += a[0]*b[0] + a[1]*b[1] + a[2]*b[2] + a[3]*b[3];
    }
    s_ws[t] = acc + mod_b[ic];
}

// ---------------- kernel 2: Wmod bf16, fragment-lane order ----------------
// Layout: [g(4)][ocb(4)][wr(2)][ch(16)][tap(9)][m(4)][lane(64)][e(8)]
// oc = ocb*128 + wr*64 + m*16 + (lane&15) ; ic = ch*32 + (lane>>4)*8 + e
__global__ void k_wmod(const float* __restrict__ weight, const float* __restrict__ demod,
                       const float* __restrict__ s_ws, short* __restrict__ wmod) {
    int t = blockIdx.x * 256 + threadIdx.x;     // [0, 131072)
    int lane = t & 63; int r = t >> 6;
    int m = r & 3; r >>= 2;
    int ch = r & 15; r >>= 4;
    int wr = r & 1; r >>= 1;
    int ocb = r & 3; r >>= 2;
    int g = r & 3;
    int oc  = ocb*128 + wr*64 + m*16 + (lane & 15);
    int ic0 = ch*32 + (lane >> 4)*8;
    const float* wp = weight + (size_t)(oc*512 + ic0)*9;   // 72 contiguous floats
    float sv[8];
#pragma unroll
    for (int e = 0; e < 8; ++e) sv[e] = s_ws[(g << 9) + ic0 + e] * demod[ic0 + e];
    short* base = wmod + ((size_t)((g*4 + ocb)*2 + wr)) * 294912 + ((size_t)m << 9) + (lane << 3);
#pragma unroll
    for (int tp = 0; tp < 9; ++tp) {
        bf16x8 pk;
#pragma unroll
        for (int e = 0; e < 8; ++e) pk[e] = (short)f2bf(wp[e*9 + tp] * sv[e]);
        *(bf16x8*)&base[(size_t)(ch*9 + tp) << 11] = pk;
    }
}

// ---------------- kernel 2b: x fp32 NCHW -> bf16 swizzled [ch][px][k][e] ---
// xb row (nb,g,y): [ch(16)][px(64)][k(4)][e(8)]; physical k holds logical
// k' = k ^ ((px>>1)&3)  (bank swizzle baked into global layout)
__global__ __launch_bounds__(256) void k_xcast(const float* __restrict__ x,
                                               short* __restrict__ xb) {
    __shared__ short Ls[64 * 520];      // row stride 520 shorts (16B-aligned)
    const int tid = threadIdx.x;
    const int y = blockIdx.x, g = blockIdx.y, nb = blockIdx.z;
    const float* src = x + (((size_t)(nb * 2048 + (g << 9))) << 12) + (y << 6);
#pragma unroll
    for (int it = 0; it < 32; ++it) {
        int j = it * 256 + tid;         // (ic, px-quad)
        int ic = j >> 4, p4 = j & 15;
        f32x4 v = *(const f32x4*)(src + ((size_t)ic << 12) + (p4 << 2));
        int kk = (ic >> 3) & 3;
        int fb = (ic >> 5) * 32 + (ic & 7);    // ch*32 + e
#pragma unroll
        for (int c = 0; c < 4; ++c) {
            int px = (p4 << 2) + c;
            int k = kk ^ ((px >> 1) & 3);
            Ls[px * 520 + fb + k * 8] = (short)f2bf(v[c]);
        }
    }
    __syncthreads();
    short* dstb = xb + ((size_t)((nb * 4 + g) * 64 + y) << 15);
#pragma unroll
    for (int it = 0; it < 16; ++it) {
        int j = it * 256 + tid;         // (ch,px,k)
        int ch = j >> 8, px = (j >> 2) & 63, k = j & 3;
        *(bf16x8*)&dstb[(size_t)j << 3] = *(const bf16x8*)&Ls[px * 520 + ch * 32 + k * 8];
    }
}

// ---------------- kernel 3: main implicit-GEMM conv (16x16x32 MFMA) --------
// Block 128oc x 256px (4 image rows), 8 waves (wr2 x wc4), each 64oc x 64px
// (acc 4x4 = 64 AGPR). BK=32, 16 chunks. Same per-wave engine as R11.
// RATIONALE (R12 arithmetic): per CU per chunk, wall 17.5k cyc = W-stream
// time (16 waves x 9 taps x 4KB = 576KB from L2/L3). Doubling px per block
// halves blocks per W slice AND gives 4-way wc L1 dedup of W lines ->
// distinct W streams per CU halve. LDS/MFMA per CU unchanged (clean test).
// X: 6 halo rows staged, 24 global_load_lds spread 3/wave, double-buffered
// LDS 2 x 25344B. Barrier = s_waitcnt vmcnt(4) + s_barrier (T4, 4 newest =
// next tap's W). setprio around MFMA (T5). 2 blocks/CU (16 waves).
__global__ __launch_bounds__(512, 4) void k_conv(const short* __restrict__ xb,
                                                 const short* __restrict__ wmod,
                                                 float* __restrict__ out) {
    __shared__ __align__(16) short Xs[2 * 12672];   // 50688 B

    const int tid  = threadIdx.x;
    const int lane = tid & 63;
    const int wv   = tid >> 6;            // 0..7
    const int wr   = wv >> 2, wc = wv & 3;
    const int l15  = lane & 15;
    const int l4   = lane >> 4;
    const int ocb  = blockIdx.x >> 4, rowb = blockIdx.x & 15;   // rowb 0..15
    const int g    = blockIdx.y, nb = blockIdx.z;
    const int y0   = rowb << 2;           // 4 image rows per block

    const short* xbg = xb + ((size_t)((nb * 4 + g) * 64) << 15);
    const short* wg  = wmod + ((size_t)((g * 4 + ocb) * 2 + wr)) * 294912;
    float* outg = out + (((size_t)(nb * 2048 + (g << 9) + ocb * 128)) << 12) + (rowb << 8);

    // staging descriptors: 24 insts (6 rows x 4 quads) over 8 waves = 3/wave
    const short* sB[3]; int dO[3]; bool ok[3];
#pragma unroll
    for (int i = 0; i < 3; ++i) {
        const int id = wv * 3 + i;        // 0..23
        const int row = id >> 2, q = id & 3;
        const int gy = y0 - 1 + row;      // y0-1 .. y0+4
        ok[i] = (gy >= 0 && gy <= 63);
        sB[i] = xbg + ((size_t)(ok[i] ? gy : 0) << 15) + (q << 9) + (lane << 3);
        dO[i] = (row * 66 + 1 + (q << 4)) << 5;
    }

    const short* wp = wg + (lane << 3);   // depth-1 W pipeline pointer

    // zero both buffers (pad slots + out-of-range halo rows stay 0 forever)
    for (int i = tid; i < 6336; i += 512) ((u64*)Xs)[i] = 0ull;

    f32x4 acc[4][4];
#pragma unroll
    for (int m = 0; m < 4; ++m)
#pragma unroll
        for (int nn = 0; nn < 4; ++nn) acc[m][nn] = (f32x4){0.f, 0.f, 0.f, 0.f};

    __syncthreads();                    // zeros visible before any gload_lds lands

    // prologue: stage chunk 0 -> buf 0 (oldest in vmcnt), then W tap-0 prefetch
#pragma unroll
    for (int i = 0; i < 3; ++i)
        if (ok[i])
            __builtin_amdgcn_global_load_lds(
                (const __attribute__((address_space(1))) void*)(sB[i]),
                (__attribute__((address_space(3))) void*)(Xs + dO[i]), 16, 0, 0);
    __builtin_amdgcn_sched_barrier(0);
    bf16x8 na0 = *(const bf16x8*)(wp);
    bf16x8 na1 = *(const bf16x8*)(wp + 512);
    bf16x8 na2 = *(const bf16x8*)(wp + 1024);
    bf16x8 na3 = *(const bf16x8*)(wp + 1536);
    wp += 2048;

#pragma unroll 1
    for (int ch = 0; ch < 16; ++ch) {
        // T4 barrier: all but the 4 newest (next tap's W) have landed
        asm volatile("s_waitcnt vmcnt(4)" ::: "memory");
        __builtin_amdgcn_s_barrier();
        __builtin_amdgcn_sched_barrier(0);
        if (ch < 15) {                  // stage next chunk into other buffer
            const int chN = ch + 1;
            short* dbase = Xs + ((chN & 1) ? 12672 : 0);
#pragma unroll
            for (int i = 0; i < 3; ++i)
                if (ok[i])
                    __builtin_amdgcn_global_load_lds(
                        (const __attribute__((address_space(1))) void*)(sB[i] + ((size_t)chN << 11)),
                        (__attribute__((address_space(3))) void*)(dbase + dO[i]), 16, 0, 0);
        }
        __builtin_amdgcn_sched_barrier(0);   // pin stage issue before tap work
        const int bb = (ch & 1) * 12672;

        // per-dx B base offsets at dy=-1 (buffer row = wc); per tap add
        // (dy+1)*2112 shorts. Swizzle: physical k = l4 ^ (((l15+dx)>>1)&3).
        int pB[3];
#pragma unroll
        for (int d = 0; d < 3; ++d) {
            const int dx = d - 1;
            pB[d] = bb + ((wc * 66 + 1 + dx + l15) << 5)
                  + ((l4 ^ (((l15 + dx) >> 1) & 3)) << 3);
        }

#pragma unroll
        for (int tap = 0; tap < 9; ++tap) {
            // depth-1 W pipeline: consume na, load next tap
            bf16x8 ca0 = na0, ca1 = na1, ca2 = na2, ca3 = na3;
            na0 = *(const bf16x8*)(wp);
            na1 = *(const bf16x8*)(wp + 512);
            na2 = *(const bf16x8*)(wp + 1024);
            na3 = *(const bf16x8*)(wp + 1536);
            wp += 2048;

            const int p0 = pB[tap % 3] + (tap / 3) * 2112;
            bf16x8 b0 = *(const bf16x8*)&Xs[p0];
            bf16x8 b1 = *(const bf16x8*)&Xs[p0 + 512];
            bf16x8 b2 = *(const bf16x8*)&Xs[p0 + 1024];
            bf16x8 b3 = *(const bf16x8*)&Xs[p0 + 1536];

            __builtin_amdgcn_s_setprio(1);
            acc[0][0] = __builtin_amdgcn_mfma_f32_16x16x32_bf16(ca0, b0, acc[0][0], 0, 0, 0);
            acc[1][0] = __builtin_amdgcn_mfma_f32_16x16x32_bf16(ca1, b0, acc[1][0], 0, 0, 0);
            acc[2][0] = __builtin_amdgcn_mfma_f32_16x16x32_bf16(ca2, b0, acc[2][0], 0, 0, 0);
            acc[3][0] = __builtin_amdgcn_mfma_f32_16x16x32_bf16(ca3, b0, acc[3][0], 0, 0, 0);
            acc[0][1] = __builtin_amdgcn_mfma_f32_16x16x32_bf16(ca0, b1, acc[0][1], 0, 0, 0);
            acc[1][1] = __builtin_amdgcn_mfma_f32_16x16x32_bf16(ca1, b1, acc[1][1], 0, 0, 0);
            acc[2][1] = __builtin_amdgcn_mfma_f32_16x16x32_bf16(ca2, b1, acc[2][1], 0, 0, 0);
            acc[3][1] = __builtin_amdgcn_mfma_f32_16x16x32_bf16(ca3, b1, acc[3][1], 0, 0, 0);
            acc[0][2] = __builtin_amdgcn_mfma_f32_16x16x32_bf16(ca0, b2, acc[0][2], 0, 0, 0);
            acc[1][2] = __builtin_amdgcn_mfma_f32_16x16x32_bf16(ca1, b2, acc[1][2], 0, 0, 0);
            acc[2][2] = __builtin_amdgcn_mfma_f32_16x16x32_bf16(ca2, b2, acc[2][2], 0, 0, 0);
            acc[3][2] = __builtin_amdgcn_mfma_f32_16x16x32_bf16(ca3, b2, acc[3][2], 0, 0, 0);
            acc[0][3] = __builtin_amdgcn_mfma_f32_16x16x32_bf16(ca0, b3, acc[0][3], 0, 0, 0);
            acc[1][3] = __builtin_amdgcn_mfma_f32_16x16x32_bf16(ca1, b3, acc[1][3], 0, 0, 0);
            acc[2][3] = __builtin_amdgcn_mfma_f32_16x16x32_bf16(ca2, b3, acc[2][3], 0, 0, 0);
            acc[3][3] = __builtin_amdgcn_mfma_f32_16x16x32_bf16(ca3, b3, acc[3][3], 0, 0, 0);
            __builtin_amdgcn_s_setprio(0);
        }
    }

    // ---- epilogue: C/D layout col=lane&15 (pixel), row=(lane>>4)*4+r (oc) ----
#pragma unroll
    for (int m = 0; m < 4; ++m)
#pragma unroll
        for (int nn = 0; nn < 4; ++nn) {
            const int oc = (wr << 6) + (m << 4) + (l4 << 2);
            const int p  = (wc << 6) + (nn << 4) + l15;
            float* dst = outg + ((size_t)oc << 12) + p;
#pragma unroll
            for (int r = 0; r < 4; ++r) dst[(size_t)r << 12] = acc[m][nn][r];
        }
}

extern "C" void kernel_launch(void* const* d_in, const int* in_sizes, int n_in,
                              void* d_out, int out_size, void* d_ws, size_t ws_size,
                              hipStream_t stream) {
    const float* x      = (const float*)d_in[0];
    const float* style  = (const float*)d_in[1];
    const float* weight = (const float*)d_in[2];
    const float* demod  = (const float*)d_in[3];
    const float* mod_w  = (const float*)d_in[4];
    const float* mod_b  = (const float*)d_in[5];
    float* out = (float*)d_out;

    float* s_ws = (float*)d_ws;                           // 8 KB
    short* wmod = (short*)((char*)d_ws + 8192);           // 18.9 MB
    short* xbuf = (short*)((char*)d_ws + 8192 + 18874368);// 67.1 MB (total ~86 MB)

    hipLaunchKernelGGL(k_style, dim3(8), dim3(256), 0, stream, style, mod_w, mod_b, s_ws);
    hipLaunchKernelGGL(k_wmod, dim3(512), dim3(256), 0, stream, weight, demod, s_ws, wmod);
    hipLaunchKernelGGL(k_xcast, dim3(64, 4, 4), dim3(256), 0, stream, x, xbuf);
    hipLaunchKernelGGL(k_conv, dim3(64, 4, 4), dim3(512), 0, stream, xbuf, wmod, out);
}

// Round 14
// 313.613 us; speedup vs baseline: 1.0191x; 1.0055x over previous
//
#include <hip/hip_runtime.h>

typedef __attribute__((ext_vector_type(4))) float f32x4;
typedef __attribute__((ext_vector_type(8))) short bf16x8;
typedef unsigned long long u64;
typedef unsigned short u16;
typedef unsigned int u32;

// round-to-nearest-even f32 -> bf16 bits
static __device__ __forceinline__ u16 f2bf(float f) {
    u32 u = __float_as_uint(f);
    u += 0x7fffu + ((u >> 16) & 1u);
    return (u16)(u >> 16);
}

// ---------------- kernel 1: s[g][ic] = style[g] . mod_w[ic] + mod_b[ic] ----
__global__ void k_style(const float* __restrict__ style, const float* __restrict__ mod_w,
                        const float* __restrict__ mod_b, float* __restrict__ s_ws) {
    int t = blockIdx.x * 256 + threadIdx.x;     // 0..2047
    int g = t >> 9, ic = t & 511;
    const f32x4* st = (const f32x4*)(style + (g << 9));
    const f32x4* mw = (const f32x4*)(mod_w + (ic << 9));
    float acc = 0.f;
#pragma unroll 4
    for (int d = 0; d < 128; ++d) {
        f32x4 a = st[d], b = mw[d];
        acc += a[0]*b[0] + a[1]*b[1] + a[2]*b[2] + a[3]*b[3];
    }
    s_ws[t] = acc + mod_b[ic];
}

// ---------------- kernel 2: Wmod bf16, fragment-lane order ----------------
// Layout: [g(4)][ocb(2)][wr(2)][ch(16)][tap(9)][m(8)][lane(64)][e(8)]
// oc = ocb*256 + wr*128 + m*16 + (lane&15) ; ic = ch*32 + (lane>>4)*8 + e
__global__ void k_wmod(const float* __restrict__ weight, const float* __restrict__ demod,
                       const float* __restrict__ s_ws, short* __restrict__ wmod) {
    int t = blockIdx.x * 256 + threadIdx.x;     // [0, 262144)
    int lane = t & 63; int r = t >> 6;
    int m = r & 7; r >>= 3;
    int ch = r & 15; r >>= 4;
    int wr = r & 1; r >>= 1;
    int ocb = r & 1; r >>= 1;
    int g = r & 3;
    int oc  = ocb*256 + wr*128 + m*16 + (lane & 15);
    int ic0 = ch*32 + (lane >> 4)*8;
    const float* wp = weight + (size_t)(oc*512 + ic0)*9;   // 72 contiguous floats
    float sv[8];
#pragma unroll
    for (int e = 0; e < 8; ++e) sv[e] = s_ws[(g << 9) + ic0 + e] * demod[ic0 + e];
    short* base = wmod + ((size_t)((g*2 + ocb)*2 + wr)) * 589824 + ((size_t)m << 9) + (lane << 3);
#pragma unroll
    for (int tp = 0; tp < 9; ++tp) {
        bf16x8 pk;
#pragma unroll
        for (int e = 0; e < 8; ++e) pk[e] = (short)f2bf(wp[e*9 + tp] * sv[e]);
        *(bf16x8*)&base[(size_t)(ch*9 + tp) << 12] = pk;
    }
}

// ---------------- kernel 2b: x fp32 NCHW -> bf16 swizzled [ch][px][k][e] ---
// xb row (nb,g,y): [ch(16)][px(64)][k(4)][e(8)]; physical k holds logical
// k' = k ^ ((px>>1)&3)  (bank swizzle baked into global layout)
__global__ __launch_bounds__(256) void k_xcast(const float* __restrict__ x,
                                               short* __restrict__ xb) {
    __shared__ short Ls[64 * 520];      // row stride 520 shorts (16B-aligned)
    const int tid = threadIdx.x;
    const int y = blockIdx.x, g = blockIdx.y, nb = blockIdx.z;
    const float* src = x + (((size_t)(nb * 2048 + (g << 9))) << 12) + (y << 6);
#pragma unroll
    for (int it = 0; it < 32; ++it) {
        int j = it * 256 + tid;         // (ic, px-quad)
        int ic = j >> 4, p4 = j & 15;
        f32x4 v = *(const f32x4*)(src + ((size_t)ic << 12) + (p4 << 2));
        int kk = (ic >> 3) & 3;
        int fb = (ic >> 5) * 32 + (ic & 7);    // ch*32 + e
#pragma unroll
        for (int c = 0; c < 4; ++c) {
            int px = (p4 << 2) + c;
            int k = kk ^ ((px >> 1) & 3);
            Ls[px * 520 + fb + k * 8] = (short)f2bf(v[c]);
        }
    }
    __syncthreads();
    short* dstb = xb + ((size_t)((nb * 4 + g) * 64 + y) << 15);
#pragma unroll
    for (int it = 0; it < 16; ++it) {
        int j = it * 256 + tid;         // (ch,px,k)
        int ch = j >> 8, px = (j >> 2) & 63, k = j & 3;
        *(bf16x8*)&dstb[(size_t)j << 3] = *(const bf16x8*)&Ls[px * 520 + ch * 32 + k * 8];
    }
}

// ---------------- kernel 3: main implicit-GEMM conv (16x16x32 MFMA) --------
// Block 256oc x 128px (2 rows), 4 waves (wr2 x wc2), each 128oc x 64px
// (acc 8x4 = 128 AGPR). BK=32, 16 chunks.
// RATIONALE (R13 sum-wall model, fits 1944 cyc/step = MFMA 1242 + LDS 768):
// phase-locked waves serialize the MFMA and LDS pipes; reduce the LDS term
// per MFMA 2x by feeding 32 MFMAs from the same 4 ds_read_b128 (wave owns
// 128 oc). Predicted step 1626 cyc -> ~195 us.
// W: global->reg depth-1, 8 frags/tap (vmcnt(8) barrier keeps next tap's W
// in flight). X: global_load_lds double-buffered (identical to R11).
// Grid 1024 = 4 blocks/CU, 2 resident rounds (2 waves/SIMD at ~228 regs).
__global__ __launch_bounds__(256, 2) void k_conv(const short* __restrict__ xb,
                                                 const short* __restrict__ wmod,
                                                 float* __restrict__ out) {
    __shared__ __align__(16) short Xs[2 * 8448];   // 33792 B

    const int tid  = threadIdx.x;
    const int lane = tid & 63;
    const int wv   = tid >> 6;
    const int wr   = wv >> 1, wc = wv & 1;
    const int l15  = lane & 15;
    const int l4   = lane >> 4;
    const int ocb  = blockIdx.x >> 5, rowb = blockIdx.x & 31;   // ocb 0..1
    const int g    = blockIdx.y, nb = blockIdx.z;
    const int y0   = rowb << 1;

    const short* xbg = xb + ((size_t)((nb * 4 + g) * 64) << 15);
    const short* wg  = wmod + ((size_t)((g * 2 + ocb) * 2 + wr)) * 589824;
    float* outg = out + (((size_t)(nb * 2048 + (g << 9) + (ocb << 8))) << 12) + (rowb << 7);

    // staging: this wave stages image row gy = y0-1+wv (4 rows for 2 outputs)
    const int gy = y0 - 1 + wv;
    const bool srow = (gy >= 0 && gy <= 63);
    const short* xsrc = xbg + ((size_t)(srow ? gy : 0) << 15) + (lane << 3);
    short* xdst0 = Xs + ((wv * 66 + 1) << 5);

    // W pipeline: per-lane pointer, 8 frag imm offsets, tap stride 4096 shorts.
    // No end-clamp: the 1-tap over-read lands in wmod/xbuf ws memory (unused).
    const short* wp = wg + (lane << 3);

    // zero both buffers (pad slots + out-of-range halo rows stay 0 forever)
    for (int i = tid; i < 4224; i += 256) ((u64*)Xs)[i] = 0ull;

    f32x4 acc[8][4];
#pragma unroll
    for (int m = 0; m < 8; ++m)
#pragma unroll
        for (int nn = 0; nn < 4; ++nn) acc[m][nn] = (f32x4){0.f, 0.f, 0.f, 0.f};

    __syncthreads();                    // zeros visible before any gload_lds lands

    // prologue: stage chunk 0 -> buf 0 (oldest in vmcnt), W tap-0 prefetch
    if (srow) {
#pragma unroll
        for (int q = 0; q < 4; ++q)
            __builtin_amdgcn_global_load_lds(
                (const __attribute__((address_space(1))) void*)(xsrc + (q << 9)),
                (__attribute__((address_space(3))) void*)(xdst0 + (q << 9)), 16, 0, 0);
    }
    __builtin_amdgcn_sched_barrier(0);
    bf16x8 na0 = *(const bf16x8*)(wp);
    bf16x8 na1 = *(const bf16x8*)(wp + 512);
    bf16x8 na2 = *(const bf16x8*)(wp + 1024);
    bf16x8 na3 = *(const bf16x8*)(wp + 1536);
    bf16x8 na4 = *(const bf16x8*)(wp + 2048);
    bf16x8 na5 = *(const bf16x8*)(wp + 2560);
    bf16x8 na6 = *(const bf16x8*)(wp + 3072);
    bf16x8 na7 = *(const bf16x8*)(wp + 3584);
    wp += 4096;

#pragma unroll 1
    for (int ch = 0; ch < 16; ++ch) {
        // T4 barrier: all but the 8 newest (next tap's W) have landed
        asm volatile("s_waitcnt vmcnt(8)" ::: "memory");
        __builtin_amdgcn_s_barrier();
        __builtin_amdgcn_sched_barrier(0);
        if (ch < 15 && srow) {          // stage next chunk into other buffer
            const short* s = xsrc + ((size_t)(ch + 1) << 11);
            short* d = xdst0 + (((ch + 1) & 1) ? 8448 : 0);
#pragma unroll
            for (int q = 0; q < 4; ++q)
                __builtin_amdgcn_global_load_lds(
                    (const __attribute__((address_space(1))) void*)(s + (q << 9)),
                    (__attribute__((address_space(3))) void*)(d + (q << 9)), 16, 0, 0);
        }
        __builtin_amdgcn_sched_barrier(0);   // pin stage issue before tap work
        const int bb = (ch & 1) * 8448;

        // per-dx B base offsets at dy=-1 (buffer row = wc); per tap add
        // (dy+1)*2112 shorts. Swizzle: physical k = l4 ^ (((l15+dx)>>1)&3).
        int pB[3];
#pragma unroll
        for (int d = 0; d < 3; ++d) {
            const int dx = d - 1;
            pB[d] = bb + ((wc * 66 + 1 + dx + l15) << 5)
                  + ((l4 ^ (((l15 + dx) >> 1) & 3)) << 3);
        }

#pragma unroll
        for (int tap = 0; tap < 9; ++tap) {
            // depth-1 W pipeline: consume na, load next tap's 8 frags
            bf16x8 ca0 = na0, ca1 = na1, ca2 = na2, ca3 = na3;
            bf16x8 ca4 = na4, ca5 = na5, ca6 = na6, ca7 = na7;
            na0 = *(const bf16x8*)(wp);
            na1 = *(const bf16x8*)(wp + 512);
            na2 = *(const bf16x8*)(wp + 1024);
            na3 = *(const bf16x8*)(wp + 1536);
            na4 = *(const bf16x8*)(wp + 2048);
            na5 = *(const bf16x8*)(wp + 2560);
            na6 = *(const bf16x8*)(wp + 3072);
            na7 = *(const bf16x8*)(wp + 3584);
            wp += 4096;

            const int p0 = pB[tap % 3] + (tap / 3) * 2112;
            bf16x8 b0 = *(const bf16x8*)&Xs[p0];
            bf16x8 b1 = *(const bf16x8*)&Xs[p0 + 512];
            bf16x8 b2 = *(const bf16x8*)&Xs[p0 + 1024];
            bf16x8 b3 = *(const bf16x8*)&Xs[p0 + 1536];

            __builtin_amdgcn_s_setprio(1);
            acc[0][0] = __builtin_amdgcn_mfma_f32_16x16x32_bf16(ca0, b0, acc[0][0], 0, 0, 0);
            acc[1][0] = __builtin_amdgcn_mfma_f32_16x16x32_bf16(ca1, b0, acc[1][0], 0, 0, 0);
            acc[2][0] = __builtin_amdgcn_mfma_f32_16x16x32_bf16(ca2, b0, acc[2][0], 0, 0, 0);
            acc[3][0] = __builtin_amdgcn_mfma_f32_16x16x32_bf16(ca3, b0, acc[3][0], 0, 0, 0);
            acc[4][0] = __builtin_amdgcn_mfma_f32_16x16x32_bf16(ca4, b0, acc[4][0], 0, 0, 0);
            acc[5][0] = __builtin_amdgcn_mfma_f32_16x16x32_bf16(ca5, b0, acc[5][0], 0, 0, 0);
            acc[6][0] = __builtin_amdgcn_mfma_f32_16x16x32_bf16(ca6, b0, acc[6][0], 0, 0, 0);
            acc[7][0] = __builtin_amdgcn_mfma_f32_16x16x32_bf16(ca7, b0, acc[7][0], 0, 0, 0);
            acc[0][1] = __builtin_amdgcn_mfma_f32_16x16x32_bf16(ca0, b1, acc[0][1], 0, 0, 0);
            acc[1][1] = __builtin_amdgcn_mfma_f32_16x16x32_bf16(ca1, b1, acc[1][1], 0, 0, 0);
            acc[2][1] = __builtin_amdgcn_mfma_f32_16x16x32_bf16(ca2, b1, acc[2][1], 0, 0, 0);
            acc[3][1] = __builtin_amdgcn_mfma_f32_16x16x32_bf16(ca3, b1, acc[3][1], 0, 0, 0);
            acc[4][1] = __builtin_amdgcn_mfma_f32_16x16x32_bf16(ca4, b1, acc[4][1], 0, 0, 0);
            acc[5][1] = __builtin_amdgcn_mfma_f32_16x16x32_bf16(ca5, b1, acc[5][1], 0, 0, 0);
            acc[6][1] = __builtin_amdgcn_mfma_f32_16x16x32_bf16(ca6, b1, acc[6][1], 0, 0, 0);
            acc[7][1] = __builtin_amdgcn_mfma_f32_16x16x32_bf16(ca7, b1, acc[7][1], 0, 0, 0);
            acc[0][2] = __builtin_amdgcn_mfma_f32_16x16x32_bf16(ca0, b2, acc[0][2], 0, 0, 0);
            acc[1][2] = __builtin_amdgcn_mfma_f32_16x16x32_bf16(ca1, b2, acc[1][2], 0, 0, 0);
            acc[2][2] = __builtin_amdgcn_mfma_f32_16x16x32_bf16(ca2, b2, acc[2][2], 0, 0, 0);
            acc[3][2] = __builtin_amdgcn_mfma_f32_16x16x32_bf16(ca3, b2, acc[3][2], 0, 0, 0);
            acc[4][2] = __builtin_amdgcn_mfma_f32_16x16x32_bf16(ca4, b2, acc[4][2], 0, 0, 0);
            acc[5][2] = __builtin_amdgcn_mfma_f32_16x16x32_bf16(ca5, b2, acc[5][2], 0, 0, 0);
            acc[6][2] = __builtin_amdgcn_mfma_f32_16x16x32_bf16(ca6, b2, acc[6][2], 0, 0, 0);
            acc[7][2] = __builtin_amdgcn_mfma_f32_16x16x32_bf16(ca7, b2, acc[7][2], 0, 0, 0);
            acc[0][3] = __builtin_amdgcn_mfma_f32_16x16x32_bf16(ca0, b3, acc[0][3], 0, 0, 0);
            acc[1][3] = __builtin_amdgcn_mfma_f32_16x16x32_bf16(ca1, b3, acc[1][3], 0, 0, 0);
            acc[2][3] = __builtin_amdgcn_mfma_f32_16x16x32_bf16(ca2, b3, acc[2][3], 0, 0, 0);
            acc[3][3] = __builtin_amdgcn_mfma_f32_16x16x32_bf16(ca3, b3, acc[3][3], 0, 0, 0);
            acc[4][3] = __builtin_amdgcn_mfma_f32_16x16x32_bf16(ca4, b3, acc[4][3], 0, 0, 0);
            acc[5][3] = __builtin_amdgcn_mfma_f32_16x16x32_bf16(ca5, b3, acc[5][3], 0, 0, 0);
            acc[6][3] = __builtin_amdgcn_mfma_f32_16x16x32_bf16(ca6, b3, acc[6][3], 0, 0, 0);
            acc[7][3] = __builtin_amdgcn_mfma_f32_16x16x32_bf16(ca7, b3, acc[7][3], 0, 0, 0);
            __builtin_amdgcn_s_setprio(0);
        }
    }

    // ---- epilogue: C/D layout col=lane&15 (pixel), row=(lane>>4)*4+r (oc) ----
#pragma unroll
    for (int m = 0; m < 8; ++m)
#pragma unroll
        for (int nn = 0; nn < 4; ++nn) {
            const int oc = (wr << 7) + (m << 4) + (l4 << 2);
            const int p  = (wc << 6) + (nn << 4) + l15;
            float* dst = outg + ((size_t)oc << 12) + p;
#pragma unroll
            for (int r = 0; r < 4; ++r) dst[(size_t)r << 12] = acc[m][nn][r];
        }
}

extern "C" void kernel_launch(void* const* d_in, const int* in_sizes, int n_in,
                              void* d_out, int out_size, void* d_ws, size_t ws_size,
                              hipStream_t stream) {
    const float* x      = (const float*)d_in[0];
    const float* style  = (const float*)d_in[1];
    const float* weight = (const float*)d_in[2];
    const float* demod  = (const float*)d_in[3];
    const float* mod_w  = (const float*)d_in[4];
    const float* mod_b  = (const float*)d_in[5];
    float* out = (float*)d_out;

    float* s_ws = (float*)d_ws;                           // 8 KB
    short* wmod = (short*)((char*)d_ws + 8192);           // 18.9 MB
    short* xbuf = (short*)((char*)d_ws + 8192 + 18874368);// 67.1 MB (total ~86 MB)

    hipLaunchKernelGGL(k_style, dim3(8), dim3(256), 0, stream, style, mod_w, mod_b, s_ws);
    hipLaunchKernelGGL(k_wmod, dim3(1024), dim3(256), 0, stream, weight, demod, s_ws, wmod);
    hipLaunchKernelGGL(k_xcast, dim3(64, 4, 4), dim3(256), 0, stream, x, xbuf);
    hipLaunchKernelGGL(k_conv, dim3(64, 4, 4), dim3(256), 0, stream, xbuf, wmod, out);
}

// Round 15
// 305.033 us; speedup vs baseline: 1.0478x; 1.0281x over previous
//
#include <hip/hip_runtime.h>

typedef __attribute__((ext_vector_type(4))) float f32x4;
typedef __attribute__((ext_vector_type(8))) short bf16x8;
typedef unsigned long long u64;
typedef unsigned short u16;
typedef unsigned int u32;

// round-to-nearest-even f32 -> bf16 bits
static __device__ __forceinline__ u16 f2bf(float f) {
    u32 u = __float_as_uint(f);
    u += 0x7fffu + ((u >> 16) & 1u);
    return (u16)(u >> 16);
}

// ---------------- kernel 1: s[g][ic] = style[g] . mod_w[ic] + mod_b[ic] ----
__global__ void k_style(const float* __restrict__ style, const float* __restrict__ mod_w,
                        const float* __restrict__ mod_b, float* __restrict__ s_ws) {
    int t = blockIdx.x * 256 + threadIdx.x;     // 0..2047
    int g = t >> 9, ic = t & 511;
    const f32x4* st = (const f32x4*)(style + (g << 9));
    const f32x4* mw = (const f32x4*)(mod_w + (ic << 9));
    float acc = 0.f;
#pragma unroll 4
    for (int d = 0; d < 128; ++d) {
        f32x4 a = st[d], b = mw[d];
        acc += a[0]*b[0] + a[1]*b[1] + a[2]*b[2] + a[3]*b[3];
    }
    s_ws[t] = acc + mod_b[ic];
}

// ---------------- kernel 2: Wmod bf16, fragment-lane order ----------------
// Layout: [g(4)][ocb(4)][wr(2)][ch(16)][tap(9)][m(4)][lane(64)][e(8)]
// oc = ocb*128 + wr*64 + m*16 + (lane&15) ; ic = ch*32 + (lane>>4)*8 + e
__global__ void k_wmod(const float* __restrict__ weight, const float* __restrict__ demod,
                       const float* __restrict__ s_ws, short* __restrict__ wmod) {
    int t = blockIdx.x * 256 + threadIdx.x;     // [0, 131072)
    int lane = t & 63; int r = t >> 6;
    int m = r & 3; r >>= 2;
    int ch = r & 15; r >>= 4;
    int wr = r & 1; r >>= 1;
    int ocb = r & 3; r >>= 2;
    int g = r & 3;
    int oc  = ocb*128 + wr*64 + m*16 + (lane & 15);
    int ic0 = ch*32 + (lane >> 4)*8;
    const float* wp = weight + (size_t)(oc*512 + ic0)*9;   // 72 contiguous floats
    float sv[8];
#pragma unroll
    for (int e = 0; e < 8; ++e) sv[e] = s_ws[(g << 9) + ic0 + e] * demod[ic0 + e];
    short* base = wmod + ((size_t)((g*4 + ocb)*2 + wr)) * 294912 + ((size_t)m << 9) + (lane << 3);
#pragma unroll
    for (int tp = 0; tp < 9; ++tp) {
        bf16x8 pk;
#pragma unroll
        for (int e = 0; e < 8; ++e) pk[e] = (short)f2bf(wp[e*9 + tp] * sv[e]);
        *(bf16x8*)&base[(size_t)(ch*9 + tp) << 11] = pk;
    }
}

// ---------------- kernel 2b: x fp32 NCHW -> bf16 swizzled [ch][px][k][e] ---
// Zero-LDS pure stream: each thread builds one 16B output (8 bf16 = 8
// consecutive ic at one px) from 8 coalesced global loads.
// slot (nb,g,y,ch,px,k,e) = x[ic][y][px], ic = ch*32 + (k^((px>>1)&3))*8 + e.
// Per wave-load (fixed e): 64 lanes = 16 px x 4 k -> 4 distinct ic rows x
// 64B contiguous px-runs = 4 fully-consumed cache lines (100% efficiency).
__global__ __launch_bounds__(256) void k_xcast(const float* __restrict__ x,
                                               short* __restrict__ xb) {
    int o = blockIdx.x * 256 + threadIdx.x;     // [0, 1<<22)
    int k  = o & 3, px = (o >> 2) & 63, ch = (o >> 8) & 15;
    int y  = (o >> 12) & 63, g = (o >> 18) & 3, nb = o >> 20;
    int ic0 = ch * 32 + ((k ^ ((px >> 1) & 3)) << 3);
    const float* src = x + (((size_t)(nb * 2048 + (g << 9) + ic0)) << 12) + (y << 6) + px;
    bf16x8 pk;
#pragma unroll
    for (int e = 0; e < 8; ++e)
        pk[e] = (short)f2bf(src[(size_t)e << 12]);
    ((bf16x8*)xb)[o] = pk;
}

// ---------------- kernel 3: main implicit-GEMM conv (16x16x32 MFMA) --------
// (R11 engine, unchanged — proven plateau config: 233.6 us, MfmaUtil 65,
// VGPR 64, WRITE 131 MB exact, conflicts 0.)
// Block 128oc x 128px (2 rows), 4 waves (wr2 x wc2), each 64oc x 64px
// (acc 4x4 = 64 AGPR). BK=32, 16 chunks, depth-1 W pipeline,
// global_load_lds double-buffered X, vmcnt(4)+s_barrier, setprio MFMA.
__global__ __launch_bounds__(256, 4) void k_conv(const short* __restrict__ xb,
                                                 const short* __restrict__ wmod,
                                                 float* __restrict__ out) {
    __shared__ __align__(16) short Xs[2 * 8448];   // 33792 B

    const int tid  = threadIdx.x;
    const int lane = tid & 63;
    const int wv   = tid >> 6;
    const int wr   = wv >> 1, wc = wv & 1;
    const int l15  = lane & 15;
    const int l4   = lane >> 4;
    const int ocb  = blockIdx.x >> 5, rowb = blockIdx.x & 31;
    const int g    = blockIdx.y, nb = blockIdx.z;
    const int y0   = rowb << 1;

    const short* xbg = xb + ((size_t)((nb * 4 + g) * 64) << 15);
    const short* wg  = wmod + ((size_t)((g * 4 + ocb) * 2 + wr)) * 294912;
    float* outg = out + (((size_t)(nb * 2048 + (g << 9) + ocb * 128)) << 12) + (rowb << 7);

    // staging: this wave stages image row gy = y0-1+wv
    const int gy = y0 - 1 + wv;
    const bool srow = (gy >= 0 && gy <= 63);
    const short* xsrc = xbg + ((size_t)(srow ? gy : 0) << 15) + (lane << 3);
    short* xdst0 = Xs + ((wv * 66 + 1) << 5);

    // W pipeline: per-lane pointer, imm offsets. No end-clamp: the 1-step
    // over-read past the last slice lands in wmod/xbuf ws memory (never used).
    const short* wp = wg + (lane << 3);

    // zero both buffers (pad slots + out-of-range halo rows stay 0 forever)
    for (int i = tid; i < 4224; i += 256) ((u64*)Xs)[i] = 0ull;

    f32x4 acc[4][4];
#pragma unroll
    for (int m = 0; m < 4; ++m)
#pragma unroll
        for (int nn = 0; nn < 4; ++nn) acc[m][nn] = (f32x4){0.f, 0.f, 0.f, 0.f};

    __syncthreads();                    // zeros visible before any gload_lds lands

    // prologue: stage chunk 0 -> buf 0 (oldest in vmcnt), then W tap-0 prefetch
    if (srow) {
#pragma unroll
        for (int q = 0; q < 4; ++q)
            __builtin_amdgcn_global_load_lds(
                (const __attribute__((address_space(1))) void*)(xsrc + (q << 9)),
                (__attribute__((address_space(3))) void*)(xdst0 + (q << 9)), 16, 0, 0);
    }
    __builtin_amdgcn_sched_barrier(0);
    bf16x8 na0 = *(const bf16x8*)(wp);
    bf16x8 na1 = *(const bf16x8*)(wp + 512);
    bf16x8 na2 = *(const bf16x8*)(wp + 1024);
    bf16x8 na3 = *(const bf16x8*)(wp + 1536);
    wp += 2048;

#pragma unroll 1
    for (int ch = 0; ch < 16; ++ch) {
        // T4 barrier: all but the 4 newest (next tap's W) have landed
        asm volatile("s_waitcnt vmcnt(4)" ::: "memory");
        __builtin_amdgcn_s_barrier();
        __builtin_amdgcn_sched_barrier(0);
        if (ch < 15 && srow) {          // stage next chunk into other buffer
            const short* s = xsrc + ((size_t)(ch + 1) << 11);
            short* d = xdst0 + (((ch + 1) & 1) ? 8448 : 0);
#pragma unroll
            for (int q = 0; q < 4; ++q)
                __builtin_amdgcn_global_load_lds(
                    (const __attribute__((address_space(1))) void*)(s + (q << 9)),
                    (__attribute__((address_space(3))) void*)(d + (q << 9)), 16, 0, 0);
        }
        __builtin_amdgcn_sched_barrier(0);   // pin stage issue before tap work
        const int bb = (ch & 1) * 8448;

        // per-dx B base offsets at dy=-1 (buffer row = wc); per tap add
        // (dy+1)*2112 shorts. Swizzle: physical k = l4 ^ (((l15+dx)>>1)&3).
        int pB[3];
#pragma unroll
        for (int d = 0; d < 3; ++d) {
            const int dx = d - 1;
            pB[d] = bb + ((wc * 66 + 1 + dx + l15) << 5)
                  + ((l4 ^ (((l15 + dx) >> 1) & 3)) << 3);
        }

#pragma unroll
        for (int tap = 0; tap < 9; ++tap) {
            // depth-1 W pipeline: consume na, load next tap
            bf16x8 ca0 = na0, ca1 = na1, ca2 = na2, ca3 = na3;
            na0 = *(const bf16x8*)(wp);
            na1 = *(const bf16x8*)(wp + 512);
            na2 = *(const bf16x8*)(wp + 1024);
            na3 = *(const bf16x8*)(wp + 1536);
            wp += 2048;

            const int p0 = pB[tap % 3] + (tap / 3) * 2112;
            bf16x8 b0 = *(const bf16x8*)&Xs[p0];
            bf16x8 b1 = *(const bf16x8*)&Xs[p0 + 512];
            bf16x8 b2 = *(const bf16x8*)&Xs[p0 + 1024];
            bf16x8 b3 = *(const bf16x8*)&Xs[p0 + 1536];

            __builtin_amdgcn_s_setprio(1);
            acc[0][0] = __builtin_amdgcn_mfma_f32_16x16x32_bf16(ca0, b0, acc[0][0], 0, 0, 0);
            acc[1][0] = __builtin_amdgcn_mfma_f32_16x16x32_bf16(ca1, b0, acc[1][0], 0, 0, 0);
            acc[2][0] = __builtin_amdgcn_mfma_f32_16x16x32_bf16(ca2, b0, acc[2][0], 0, 0, 0);
            acc[3][0] = __builtin_amdgcn_mfma_f32_16x16x32_bf16(ca3, b0, acc[3][0], 0, 0, 0);
            acc[0][1] = __builtin_amdgcn_mfma_f32_16x16x32_bf16(ca0, b1, acc[0][1], 0, 0, 0);
            acc[1][1] = __builtin_amdgcn_mfma_f32_16x16x32_bf16(ca1, b1, acc[1][1], 0, 0, 0);
            acc[2][1] = __builtin_amdgcn_mfma_f32_16x16x32_bf16(ca2, b1, acc[2][1], 0, 0, 0);
            acc[3][1] = __builtin_amdgcn_mfma_f32_16x16x32_bf16(ca3, b1, acc[3][1], 0, 0, 0);
            acc[0][2] = __builtin_amdgcn_mfma_f32_16x16x32_bf16(ca0, b2, acc[0][2], 0, 0, 0);
            acc[1][2] = __builtin_amdgcn_mfma_f32_16x16x32_bf16(ca1, b2, acc[1][2], 0, 0, 0);
            acc[2][2] = __builtin_amdgcn_mfma_f32_16x16x32_bf16(ca2, b2, acc[2][2], 0, 0, 0);
            acc[3][2] = __builtin_amdgcn_mfma_f32_16x16x32_bf16(ca3, b2, acc[3][2], 0, 0, 0);
            acc[0][3] = __builtin_amdgcn_mfma_f32_16x16x32_bf16(ca0, b3, acc[0][3], 0, 0, 0);
            acc[1][3] = __builtin_amdgcn_mfma_f32_16x16x32_bf16(ca1, b3, acc[1][3], 0, 0, 0);
            acc[2][3] = __builtin_amdgcn_mfma_f32_16x16x32_bf16(ca2, b3, acc[2][3], 0, 0, 0);
            acc[3][3] = __builtin_amdgcn_mfma_f32_16x16x32_bf16(ca3, b3, acc[3][3], 0, 0, 0);
            __builtin_amdgcn_s_setprio(0);
        }
    }

    // ---- epilogue: C/D layout col=lane&15 (pixel), row=(lane>>4)*4+r (oc) ----
#pragma unroll
    for (int m = 0; m < 4; ++m)
#pragma unroll
        for (int nn = 0; nn < 4; ++nn) {
            const int oc = (wr << 6) + (m << 4) + (l4 << 2);
            const int p  = (wc << 6) + (nn << 4) + l15;
            float* dst = outg + ((size_t)oc << 12) + p;
#pragma unroll
            for (int r = 0; r < 4; ++r) dst[(size_t)r << 12] = acc[m][nn][r];
        }
}

extern "C" void kernel_launch(void* const* d_in, const int* in_sizes, int n_in,
                              void* d_out, int out_size, void* d_ws, size_t ws_size,
                              hipStream_t stream) {
    const float* x      = (const float*)d_in[0];
    const float* style  = (const float*)d_in[1];
    const float* weight = (const float*)d_in[2];
    const float* demod  = (const float*)d_in[3];
    const float* mod_w  = (const float*)d_in[4];
    const float* mod_b  = (const float*)d_in[5];
    float* out = (float*)d_out;

    float* s_ws = (float*)d_ws;                           // 8 KB
    short* wmod = (short*)((char*)d_ws + 8192);           // 18.9 MB
    short* xbuf = (short*)((char*)d_ws + 8192 + 18874368);// 67.1 MB (total ~86 MB)

    hipLaunchKernelGGL(k_style, dim3(8), dim3(256), 0, stream, style, mod_w, mod_b, s_ws);
    hipLaunchKernelGGL(k_wmod, dim3(512), dim3(256), 0, stream, weight, demod, s_ws, wmod);
    hipLaunchKernelGGL(k_xcast, dim3(16384), dim3(256), 0, stream, x, xbuf);
    hipLaunchKernelGGL(k_conv, dim3(128, 4, 4), dim3(256), 0, stream, xbuf, wmod, out);
}